// Round 6
// baseline (869.297 us; speedup 1.0000x reference)
//
#include <hip/hip_runtime.h>

#define BN    64
#define KCLS  3
#define PPIX  147456
#define NB1   4096
#define CAP   8192

// streaming geometry: 64 rows x 32 chunks = 2048 blocks = 8 blocks/CU
#define BPR    32
#define F4PB   (PPIX / 4 / BPR)     // 1152 float4 groups per block (4x256 + 128 tail)

#define SCOPE __HIP_MEMORY_SCOPE_AGENT

// ---------------- workspace layout (bytes) ----------------
static const size_t OFF_NLL  = 0;                                   // 37,748,736
static const size_t OFF_CAND = OFF_NLL + (size_t)BN * PPIX * 4;     // 2 MB
static const size_t OFF_GH   = OFF_CAND + (size_t)BN * CAP * 4;     // 1 MB (zeroed)
static const size_t OFF_CCNT = OFF_GH + (size_t)BN * NB1 * 4;       // 256 B (zeroed)
static const size_t OFF_SS   = OFF_CCNT + 256;                      // 512 B (zeroed)
static const size_t OFF_ARR  = OFF_SS + 512;                        // 256 B (zeroed)
static const size_t OFF_ACC  = OFF_ARR + 256;                       // 8 B   (zeroed)
static const size_t OFF_DONE = OFF_ACC + 8;                         // 8 B   (zeroed)
static const size_t ZERO_END = OFF_DONE + 8;

__device__ __forceinline__ unsigned topk_count(const int* sp_ptr) {
    double sp = (double)sp_ptr[0];
    if (sp > 1.0) sp = 1.0;
    return (unsigned)(sp * 0.15 * (double)PPIX + (1.0 - sp) * (double)PPIX);
}

__device__ __forceinline__ float sel_nll(int t, float a, float b, float c) {
    float lp = (t == 0) ? a : ((t == 1) ? b : ((t == 2) ? c : 0.0f));
    return fmaxf(-lp, 0.0f);   // nll >= 0; kill -0.0
}

// device-scope (cross-XCD coherent) accessors for same-kernel cross-block data
__device__ __forceinline__ int ld_ai32(const int* p) {
    return __hip_atomic_load(p, __ATOMIC_RELAXED, SCOPE);
}
__device__ __forceinline__ float ld_af32(const float* p) {
    return __hip_atomic_load(p, __ATOMIC_RELAXED, SCOPE);
}
__device__ __forceinline__ double ld_af64(const double* p) {
    return __hip_atomic_load(p, __ATOMIC_RELAXED, SCOPE);
}
__device__ __forceinline__ void st_af32(float* p, float v) {
    __hip_atomic_store(p, v, __ATOMIC_RELAXED, SCOPE);
}

// ---------------- kernel 1: NLL select + store + count histogram ------------
// (byte-identical to verified r4 version, 68.5us)
__global__ __launch_bounds__(256) void k_hist1(
    const float* __restrict__ in, const int* __restrict__ tgt,
    float* __restrict__ nll, unsigned* __restrict__ cnt1)
{
    __shared__ unsigned lc[NB1];   // 16 KB -> 8 blocks/CU by LDS
    const int tid = threadIdx.x;
    for (int i = tid; i < NB1; i += 256) lc[i] = 0u;
    __syncthreads();

    const int row   = blockIdx.x / BPR;
    const int chunk = blockIdx.x % BPR;
    const float4* p0 = (const float4*)(in + (size_t)row * KCLS * PPIX);
    const float4* p1 = p0 + PPIX / 4;
    const float4* p2 = p1 + PPIX / 4;
    const int4*   t4 = (const int4*)(tgt + (size_t)row * PPIX);
    float4*       n4 = (float4*)(nll + (size_t)row * PPIX);
    const int base = chunk * F4PB;
    const bool tail = (tid < (F4PB - 4 * 256));   // tid < 128 does a 5th group

    // prefetch j=0
    int idx_c = base + tid;
    int4   t_c = t4[idx_c];
    float4 a_c = p0[idx_c];
    float4 b_c = p1[idx_c];
    float4 c_c = p2[idx_c];

    #pragma unroll
    for (int j = 0; j < 4; ++j) {
        int idx_n = 0;
        int4 t_n; float4 a_n, b_n, c_n;
        const bool have_next = (j < 3) || tail;
        if (have_next) {
            idx_n = base + (j + 1) * 256 + tid;
            t_n = t4[idx_n];
            a_n = p0[idx_n];
            b_n = p1[idx_n];
            c_n = p2[idx_n];
        }

        float4 v;
        v.x = sel_nll(t_c.x, a_c.x, b_c.x, c_c.x);
        v.y = sel_nll(t_c.y, a_c.y, b_c.y, c_c.y);
        v.z = sel_nll(t_c.z, a_c.z, b_c.z, c_c.z);
        v.w = sel_nll(t_c.w, a_c.w, b_c.w, c_c.w);
        n4[idx_c] = v;
        atomicAdd(&lc[__float_as_uint(v.x) >> 19], 1u);
        atomicAdd(&lc[__float_as_uint(v.y) >> 19], 1u);
        atomicAdd(&lc[__float_as_uint(v.z) >> 19], 1u);
        atomicAdd(&lc[__float_as_uint(v.w) >> 19], 1u);

        idx_c = idx_n; t_c = t_n; a_c = a_n; b_c = b_n; c_c = c_n;
    }

    if (tail) {
        float4 v;
        v.x = sel_nll(t_c.x, a_c.x, b_c.x, c_c.x);
        v.y = sel_nll(t_c.y, a_c.y, b_c.y, c_c.y);
        v.z = sel_nll(t_c.z, a_c.z, b_c.z, c_c.z);
        v.w = sel_nll(t_c.w, a_c.w, b_c.w, c_c.w);
        n4[idx_c] = v;
        atomicAdd(&lc[__float_as_uint(v.x) >> 19], 1u);
        atomicAdd(&lc[__float_as_uint(v.y) >> 19], 1u);
        atomicAdd(&lc[__float_as_uint(v.z) >> 19], 1u);
        atomicAdd(&lc[__float_as_uint(v.w) >> 19], 1u);
    }
    __syncthreads();

    unsigned* gc = cnt1 + (size_t)row * NB1;
    for (int i = tid; i < NB1; i += 256) {
        const unsigned cc = lc[i];
        if (cc) atomicAdd(&gc[i], cc);
    }
}

// ---------------- kernel 2: scan + parallel compact + last-block resolve ----
// 2048 blocks x 256 thr. Each block: (a) redundant level-1 scan of its row's
// ghist; (b) streams its 1/32 nll chunk: S_above f64 -> global atomic,
// bin-b1 candidates -> wave-aggregated global append; (c) bumps per-row
// arrival counter; the 32nd (last) arrival — already resident, never waits —
// resolves levels 2+3 over the candidates and does the accum/done/mean ticket.
__global__ __launch_bounds__(256) void k_finish(
    const float* __restrict__ nll, const unsigned* __restrict__ ghist,
    const int* __restrict__ sp, float* __restrict__ cand,
    int* __restrict__ ccnt, double* __restrict__ st_S,
    unsigned* __restrict__ arr, double* __restrict__ accum,
    unsigned* __restrict__ done, float* __restrict__ out)
{
    __shared__ unsigned cs[256];     // 1 KB — count-prefix scratch
    __shared__ double   dd[256];     // 2 KB — f64 reduce / sum-prefix scratch
    __shared__ unsigned lc2[1024];   // 4 KB — level-2/3 count hist
    __shared__ float    ls2[1024];   // 4 KB — level-2/3 sum hist
    __shared__ int s_b1, s_r1, s_last, s_b2, s_r2;
    __shared__ double s_S2;

    const int tid   = threadIdx.x;
    const int row   = blockIdx.x / BPR;
    const int chunk = blockIdx.x % BPR;

    // ---- level-1 scan (verified r0 k_scan logic, inline, redundant/block) --
    const unsigned* ghr = ghist + (size_t)row * NB1;
    {
        unsigned cl[16]; unsigned cacc = 0u;
        const int base = tid * 16;
        #pragma unroll
        for (int i = 0; i < 16; ++i) {
            cl[i] = ghr[NB1 - 1 - (base + i)];
            cacc += cl[i];
        }
        cs[tid] = cacc;
        __syncthreads();
        for (int off = 1; off < 256; off <<= 1) {
            unsigned t2 = (tid >= off) ? cs[tid - off] : 0u;
            __syncthreads();
            cs[tid] += t2;
            __syncthreads();
        }
        const unsigned k = topk_count(sp);
        unsigned cum = tid ? cs[tid - 1] : 0u;
        #pragma unroll
        for (int i = 0; i < 16; ++i) {
            const unsigned cb = cl[i];
            if (cum < k && cum + cb >= k) {      // exactly one (thread,i) hits
                s_b1 = NB1 - 1 - (base + i);
                s_r1 = (int)(k - cum);
            }
            cum += cb;
        }
    }
    __syncthreads();

    // ---- stream this chunk: S_above (f64) + wave-aggregated append ---------
    const unsigned b1 = (unsigned)s_b1;
    const unsigned lo = b1 << 19;
    const unsigned hi = (b1 + 1u) << 19;   // b1==4095 -> 0x80000000 > all v>=0
    const float4* n4 = (const float4*)(nll + (size_t)row * PPIX);
    int*   ccr = &ccnt[row];
    float* cr  = cand + (size_t)row * CAP;
    const int gbase = chunk * F4PB;
    const int lane  = tid & 63;

    double acc = 0.0;
    #pragma unroll
    for (int j = 0; j < 5; ++j) {
        if (j == 4 && tid >= (F4PB - 4 * 256)) break;   // tail: tid<128 only
        const float4 f = n4[gbase + j * 256 + tid];
        const float vv[4] = {f.x, f.y, f.z, f.w};
        #pragma unroll
        for (int q = 0; q < 4; ++q) {
            const unsigned u = __float_as_uint(vv[q]);
            if (u >= hi) {
                acc += (double)vv[q];
            } else if (u >= lo) {
                // wave-aggregated global append: 1 atomic per wave per hit set
                const unsigned long long m = __ballot(1);
                const int lead = (int)(__ffsll((long long)m) - 1);
                int wb = 0;
                if (lane == lead) wb = atomicAdd(ccr, __popcll(m));
                wb = __shfl(wb, lead, 64);
                const int slot = wb + __popcll(m & ((1ull << lane) - 1ull));
                if (slot < CAP) st_af32(&cr[slot], vv[q]);
            }
        }
    }
    dd[tid] = acc;
    __syncthreads();
    for (int s = 128; s > 0; s >>= 1) {
        if (tid < s) dd[tid] += dd[tid + s];
        __syncthreads();
    }
    if (tid == 0) atomicAdd(&st_S[row], dd[0]);   // native f64 global atomic
    __syncthreads();

    // ---- arrival ticket: last block of the row resolves (no waiting) -------
    if (tid == 0) {
        __threadfence();   // release this block's cand/st_S stores device-wide
        const unsigned t = __hip_atomic_fetch_add(&arr[row], 1u,
                                                  __ATOMIC_ACQ_REL, SCOPE);
        s_last = (t == (unsigned)(BPR - 1));
    }
    __syncthreads();
    if (!s_last) return;

    // ---- resolve: levels 2+3 over candidates (verified r3 math, 256 thr) ---
    int n = ld_ai32(ccr); if (n > CAP) n = CAP;

    // level 2: 1024-bin hist over bits[18:9]
    for (int i = tid; i < 1024; i += 256) { lc2[i] = 0u; ls2[i] = 0.0f; }
    __syncthreads();
    for (int i = tid; i < n; i += 256) {
        const float v = ld_af32(&cr[i]);
        const unsigned key = (__float_as_uint(v) >> 9) & 0x3FFu;
        atomicAdd(&lc2[key], 1u);
        atomicAdd(&ls2[key], v);
    }
    __syncthreads();
    {
        unsigned cl2[4]; float slv[4];
        unsigned cacc = 0u; double sacc = 0.0;
        const int base = tid * 4;
        #pragma unroll
        for (int i = 0; i < 4; ++i) {
            const int bin = 1023 - (base + i);
            cl2[i] = lc2[bin];
            slv[i] = ls2[bin];
            cacc += cl2[i];
            sacc += (double)slv[i];
        }
        cs[tid] = cacc; dd[tid] = sacc;
        __syncthreads();
        for (int off = 1; off < 256; off <<= 1) {
            unsigned tc = 0u; double td = 0.0;
            if (tid >= off) { tc = cs[tid - off]; td = dd[tid - off]; }
            __syncthreads();
            cs[tid] += tc; dd[tid] += td;
            __syncthreads();
        }
        const unsigned k2 = (unsigned)s_r1;
        unsigned cum = tid ? cs[tid - 1] : 0u;
        double   sS  = tid ? dd[tid - 1] : 0.0;
        #pragma unroll
        for (int i = 0; i < 4; ++i) {
            const unsigned cb = cl2[i];
            if (cum < k2 && cum + cb >= k2) {    // exactly one (thread,i)
                s_b2 = 1023 - (base + i);
                s_r2 = (int)(k2 - cum);
                s_S2 = sS;
            }
            cum += cb;
            sS  += (double)slv[i];
        }
    }
    __syncthreads();

    // level 3: 512-bin hist over bits[8:0], filtered to b2
    const unsigned b2 = (unsigned)s_b2;
    for (int i = tid; i < 512; i += 256) { lc2[i] = 0u; ls2[i] = 0.0f; }
    __syncthreads();
    for (int i = tid; i < n; i += 256) {
        const float v = ld_af32(&cr[i]);
        const unsigned bits = __float_as_uint(v);
        if (((bits >> 9) & 0x3FFu) == b2) {
            atomicAdd(&lc2[bits & 0x1FFu], 1u);
            atomicAdd(&ls2[bits & 0x1FFu], v);
        }
    }
    __syncthreads();
    {
        unsigned cl3[2]; float slv[2];
        unsigned cacc = 0u; double sacc = 0.0;
        const int base = tid * 2;
        #pragma unroll
        for (int i = 0; i < 2; ++i) {
            const int bin = 511 - (base + i);
            cl3[i] = lc2[bin];
            slv[i] = ls2[bin];
            cacc += cl3[i];
            sacc += (double)slv[i];
        }
        cs[tid] = cacc; dd[tid] = sacc;
        __syncthreads();
        for (int off = 1; off < 256; off <<= 1) {
            unsigned tc = 0u; double td = 0.0;
            if (tid >= off) { tc = cs[tid - off]; td = dd[tid - off]; }
            __syncthreads();
            cs[tid] += tc; dd[tid] += td;
            __syncthreads();
        }
        const unsigned k3 = (unsigned)s_r2;
        unsigned cum = tid ? cs[tid - 1] : 0u;
        double   S3  = tid ? dd[tid - 1] : 0.0;
        #pragma unroll
        for (int i = 0; i < 2; ++i) {
            const unsigned cb = cl3[i];
            if (cum < k3 && cum + cb >= k3) {    // exactly one thread finalizes
                const int      bin3 = 511 - (base + i);
                const unsigned r3   = k3 - cum;
                const float tval = __uint_as_float((b1 << 19) | (b2 << 9) | (unsigned)bin3);
                const double total = ld_af64(&st_S[row]) + s_S2 + S3
                                   + (double)r3 * (double)tval;
                atomicAdd(accum, total);         // device-scope f64 atomic
                __threadfence();
                const unsigned ticket = __hip_atomic_fetch_add(
                    done, 1u, __ATOMIC_ACQ_REL, SCOPE);
                if (ticket == BN - 1) {          // last row writes the mean
                    const double a2 = ld_af64(accum);
                    out[0] = (float)(a2 / ((double)BN * (double)topk_count(sp)));
                }
            }
            cum += cb;
            S3  += (double)slv[i];
        }
    }
}

// ======================= launch =============================================
extern "C" void kernel_launch(void* const* d_in, const int* in_sizes, int n_in,
                              void* d_out, int out_size, void* d_ws, size_t ws_size,
                              hipStream_t stream)
{
    (void)in_sizes; (void)n_in; (void)out_size; (void)ws_size;
    const float* in  = (const float*)d_in[0];
    const int*   tgt = (const int*)d_in[1];
    const int*   sp  = (const int*)d_in[2];

    char* ws = (char*)d_ws;
    float*    nll   = (float*)(ws + OFF_NLL);
    float*    cand  = (float*)(ws + OFF_CAND);
    unsigned* ghist = (unsigned*)(ws + OFF_GH);
    int*      ccnt  = (int*)(ws + OFF_CCNT);
    double*   st_S  = (double*)(ws + OFF_SS);
    unsigned* arr   = (unsigned*)(ws + OFF_ARR);
    double*   accum = (double*)(ws + OFF_ACC);
    unsigned* done  = (unsigned*)(ws + OFF_DONE);

    // zero: ghist + ccnt + st_S + arr + accum + done (contiguous)
    hipMemsetAsync(ws + OFF_GH, 0, ZERO_END - OFF_GH, stream);

    k_hist1 <<<BN * BPR, 256, 0, stream>>>(in, tgt, nll, ghist);
    k_finish<<<BN * BPR, 256, 0, stream>>>(nll, ghist, sp, cand, ccnt, st_S,
                                           arr, accum, done, (float*)d_out);
}

// Round 7
// 249.228 us; speedup vs baseline: 3.4880x; 3.4880x over previous
//
#include <hip/hip_runtime.h>

#define BN    64
#define KCLS  3
#define PPIX  147456
#define NB1   4096
#define NB3   128
#define CAP   8192

// k_hist1 geometry (verified r4): 64 rows x 32 chunks = 2048 blocks = 8/CU
#define BPR    32
#define F4PB   (PPIX / 4 / BPR)     // 1152 float4 groups per block

// compact geometry (verified r0): 64 rows x 36 chunks = 2304 blocks
#define BPR_C  36
#define F4_BLK 1024
#define PX_BLK 4096

#define SCOPE __HIP_MEMORY_SCOPE_AGENT

// ---------------- workspace layout (bytes) ----------------
static const size_t OFF_NLL  = 0;                                   // 37,748,736
static const size_t OFF_CAND = OFF_NLL + (size_t)BN * PPIX * 4;     // 2 MB
static const size_t OFF_GH   = OFF_CAND + (size_t)BN * CAP * 4;     // 1 MB (zeroed)
static const size_t OFF_CCNT = OFF_GH + (size_t)BN * NB1 * 4;       // 256 B (zeroed)
static const size_t OFF_SS   = OFF_CCNT + 256;                      // 512 B (zeroed)
static const size_t OFF_ACC  = OFF_SS + 512;                        // 8 B   (zeroed)
static const size_t OFF_DONE = OFF_ACC + 8;                         // 8 B   (zeroed)
static const size_t ZERO_END = OFF_DONE + 8;
static const size_t OFF_B1   = ZERO_END;                            // st_b1 (64 ints)
static const size_t OFF_R1   = ZERO_END + 256;                      // st_r1 (64 ints)

__device__ __forceinline__ unsigned topk_count(const int* sp_ptr) {
    double sp = (double)sp_ptr[0];
    if (sp > 1.0) sp = 1.0;
    return (unsigned)(sp * 0.15 * (double)PPIX + (1.0 - sp) * (double)PPIX);
}

__device__ __forceinline__ float sel_nll(int t, float a, float b, float c) {
    float lp = (t == 0) ? a : ((t == 1) ? b : ((t == 2) ? c : 0.0f));
    return fmaxf(-lp, 0.0f);   // nll >= 0; kill -0.0
}

// ---------------- kernel 1: NLL select + store + count histogram ------------
// (byte-identical to verified r4 version, 68.5us)
__global__ __launch_bounds__(256) void k_hist1(
    const float* __restrict__ in, const int* __restrict__ tgt,
    float* __restrict__ nll, unsigned* __restrict__ cnt1)
{
    __shared__ unsigned lc[NB1];   // 16 KB -> 8 blocks/CU by LDS
    const int tid = threadIdx.x;
    for (int i = tid; i < NB1; i += 256) lc[i] = 0u;
    __syncthreads();

    const int row   = blockIdx.x / BPR;
    const int chunk = blockIdx.x % BPR;
    const float4* p0 = (const float4*)(in + (size_t)row * KCLS * PPIX);
    const float4* p1 = p0 + PPIX / 4;
    const float4* p2 = p1 + PPIX / 4;
    const int4*   t4 = (const int4*)(tgt + (size_t)row * PPIX);
    float4*       n4 = (float4*)(nll + (size_t)row * PPIX);
    const int base = chunk * F4PB;
    const bool tail = (tid < (F4PB - 4 * 256));   // tid < 128 does a 5th group

    int idx_c = base + tid;
    int4   t_c = t4[idx_c];
    float4 a_c = p0[idx_c];
    float4 b_c = p1[idx_c];
    float4 c_c = p2[idx_c];

    #pragma unroll
    for (int j = 0; j < 4; ++j) {
        int idx_n = 0;
        int4 t_n; float4 a_n, b_n, c_n;
        const bool have_next = (j < 3) || tail;
        if (have_next) {
            idx_n = base + (j + 1) * 256 + tid;
            t_n = t4[idx_n];
            a_n = p0[idx_n];
            b_n = p1[idx_n];
            c_n = p2[idx_n];
        }

        float4 v;
        v.x = sel_nll(t_c.x, a_c.x, b_c.x, c_c.x);
        v.y = sel_nll(t_c.y, a_c.y, b_c.y, c_c.y);
        v.z = sel_nll(t_c.z, a_c.z, b_c.z, c_c.z);
        v.w = sel_nll(t_c.w, a_c.w, b_c.w, c_c.w);
        n4[idx_c] = v;
        atomicAdd(&lc[__float_as_uint(v.x) >> 19], 1u);
        atomicAdd(&lc[__float_as_uint(v.y) >> 19], 1u);
        atomicAdd(&lc[__float_as_uint(v.z) >> 19], 1u);
        atomicAdd(&lc[__float_as_uint(v.w) >> 19], 1u);

        idx_c = idx_n; t_c = t_n; a_c = a_n; b_c = b_n; c_c = c_n;
    }

    if (tail) {
        float4 v;
        v.x = sel_nll(t_c.x, a_c.x, b_c.x, c_c.x);
        v.y = sel_nll(t_c.y, a_c.y, b_c.y, c_c.y);
        v.z = sel_nll(t_c.z, a_c.z, b_c.z, c_c.z);
        v.w = sel_nll(t_c.w, a_c.w, b_c.w, c_c.w);
        n4[idx_c] = v;
        atomicAdd(&lc[__float_as_uint(v.x) >> 19], 1u);
        atomicAdd(&lc[__float_as_uint(v.y) >> 19], 1u);
        atomicAdd(&lc[__float_as_uint(v.z) >> 19], 1u);
        atomicAdd(&lc[__float_as_uint(v.w) >> 19], 1u);
    }
    __syncthreads();

    unsigned* gc = cnt1 + (size_t)row * NB1;
    for (int i = tid; i < NB1; i += 256) {
        const unsigned cc = lc[i];
        if (cc) atomicAdd(&gc[i], cc);
    }
}

// ---------------- kernel 2: per-row descending scan -> (b1, r1) -------------
// (byte-identical to verified r0 k_scan)
__global__ __launch_bounds__(256) void k_scan(
    const unsigned* __restrict__ cnt, const int* __restrict__ sp_ptr,
    int* __restrict__ st_b, int* __restrict__ st_r)
{
    const int row = blockIdx.x, tid = threadIdx.x;
    __shared__ unsigned csum[256];
    const unsigned* c = cnt + (size_t)row * NB1;

    unsigned cl[16]; unsigned cacc = 0;
    const int base = tid * 16;
    #pragma unroll
    for (int i = 0; i < 16; ++i) {
        cl[i] = c[NB1 - 1 - (base + i)];
        cacc += cl[i];
    }
    csum[tid] = cacc;
    __syncthreads();
    for (int off = 1; off < 256; off <<= 1) {
        unsigned t2 = (tid >= off) ? csum[tid - off] : 0u;
        __syncthreads();
        csum[tid] += t2;
        __syncthreads();
    }
    const unsigned k = topk_count(sp_ptr);
    unsigned cum = tid ? csum[tid - 1] : 0u;
    #pragma unroll
    for (int i = 0; i < 16; ++i) {
        const unsigned cb = cl[i];
        if (cum < k && cum + cb >= k) {      // exactly one (thread,i) hits
            st_b[row] = NB1 - 1 - (base + i);
            st_r[row] = (int)(k - cum);
        }
        cum += cb;
    }
}

// ---------------- kernel 3: S_above (f64) + compact bin-b1 candidates -------
// (byte-identical to verified r0 k_compact: LDS staging, ONE ccnt atomic per
//  block, plain stores to cand; coherence via the kernel boundary)
__global__ __launch_bounds__(256) void k_compact(
    const float* __restrict__ nll, const int* __restrict__ st_b1,
    float* __restrict__ cand, int* __restrict__ ccnt, double* __restrict__ st_S)
{
    __shared__ float  stage[PX_BLK];   // worst case: all 4096 match (16 KB)
    __shared__ double dred[256];       // 2 KB
    __shared__ int lcnt, gbase;
    const int tid = threadIdx.x;
    if (tid == 0) lcnt = 0;
    __syncthreads();

    const int row   = blockIdx.x / BPR_C;
    const int chunk = blockIdx.x % BPR_C;
    const unsigned b1 = (unsigned)st_b1[row];
    const unsigned lo = b1 << 19;
    const unsigned hi = (b1 + 1u) << 19;   // b1==4095 -> 0x80000000 > all v>=0
    const float4* n4 = (const float4*)(nll + (size_t)row * PPIX);
    const int base = chunk * F4_BLK;

    double acc = 0.0;
    #pragma unroll
    for (int j = 0; j < 4; ++j) {
        const float4 f = n4[base + j * 256 + tid];
        const float vv[4] = {f.x, f.y, f.z, f.w};
        #pragma unroll
        for (int q = 0; q < 4; ++q) {
            const unsigned u = __float_as_uint(vv[q]);
            if (u >= hi) {
                acc += (double)vv[q];
            } else if (u >= lo) {
                const int s = atomicAdd(&lcnt, 1);
                stage[s] = vv[q];
            }
        }
    }
    dred[tid] = acc;
    __syncthreads();
    for (int s = 128; s > 0; s >>= 1) {
        if (tid < s) dred[tid] += dred[tid + s];
        __syncthreads();
    }
    if (tid == 0) {
        atomicAdd(&st_S[row], dred[0]);            // native f64 global atomic
        gbase = atomicAdd(&ccnt[row], lcnt);
    }
    __syncthreads();
    const int n = lcnt, gb = gbase;
    float* cr = cand + (size_t)row * CAP;
    for (int i = tid; i < n; i += 256) {
        const int pos = gb + i;
        if (pos < CAP) cr[pos] = stage[i];
    }
}

// ---------------- kernel 4: per-row resolve (levels 2+3) + fused mean -------
// (verified r0 k_resolve + the triple-verified accum/done/mean ticket)
__global__ __launch_bounds__(256) void k_resolve(
    const float* __restrict__ cand, const int* __restrict__ ccnt,
    const int* __restrict__ st_b1, const int* __restrict__ st_r1,
    const double* __restrict__ st_S, const int* __restrict__ sp,
    double* __restrict__ accum, unsigned* __restrict__ done,
    float* __restrict__ out)
{
    __shared__ unsigned lc[NB1];
    __shared__ float    ls[NB1];
    __shared__ unsigned csum[256];
    __shared__ double   ssum[256];
    __shared__ int sb2, sr2;
    __shared__ double sS2;

    const int row = blockIdx.x, tid = threadIdx.x;
    int n = ccnt[row]; if (n > CAP) n = CAP;
    const float* cv = cand + (size_t)row * CAP;

    // ---- level 2: hist over bits[18:7] ----
    for (int i = tid; i < NB1; i += 256) { lc[i] = 0u; ls[i] = 0.0f; }
    __syncthreads();
    for (int i = tid; i < n; i += 256) {
        const float v = cv[i];
        const unsigned key = (__float_as_uint(v) >> 7) & 0xFFFu;
        atomicAdd(&lc[key], 1u);
        atomicAdd(&ls[key], v);
    }
    __syncthreads();

    unsigned cl[16]; float slv[16];
    unsigned cacc = 0; double sacc = 0.0;
    const int base = tid * 16;
    #pragma unroll
    for (int i = 0; i < 16; ++i) {
        const int bin = NB1 - 1 - (base + i);
        cl[i]  = lc[bin];
        slv[i] = ls[bin];
        cacc += cl[i];
        sacc += (double)slv[i];
    }
    csum[tid] = cacc; ssum[tid] = sacc;
    __syncthreads();
    for (int off = 1; off < 256; off <<= 1) {
        unsigned cv2 = 0; double sv = 0.0;
        if (tid >= off) { cv2 = csum[tid - off]; sv = ssum[tid - off]; }
        __syncthreads();
        csum[tid] += cv2; ssum[tid] += sv;
        __syncthreads();
    }
    const unsigned k = (unsigned)st_r1[row];
    unsigned cum = tid ? csum[tid - 1] : 0u;
    double   sS  = tid ? ssum[tid - 1] : 0.0;
    #pragma unroll
    for (int i = 0; i < 16; ++i) {
        const unsigned cb = cl[i];
        if (cum < k && cum + cb >= k) {
            sb2 = NB1 - 1 - (base + i);
            sr2 = (int)(k - cum);
            sS2 = sS;
        }
        cum += cb;
        sS  += (double)slv[i];
    }
    __syncthreads();

    // ---- level 3: 128-bin hist over bits[6:0], prefix = bits[30:7] ----
    const unsigned pref = ((unsigned)st_b1[row] << 12) | (unsigned)sb2;
    if (tid < NB3) { lc[tid] = 0u; ls[tid] = 0.0f; }
    __syncthreads();
    for (int i = tid; i < n; i += 256) {
        const float v = cv[i];
        const unsigned bits = __float_as_uint(v);
        if ((bits >> 7) == pref) {
            atomicAdd(&lc[bits & 0x7Fu], 1u);
            atomicAdd(&ls[bits & 0x7Fu], v);
        }
    }
    __syncthreads();
    if (tid == 0) {
        const unsigned k3 = (unsigned)sr2;
        unsigned cum3 = 0, r3 = 0; int b3 = 0; double S3 = 0.0;
        for (int bin = NB3 - 1; bin >= 0; --bin) {
            const unsigned cb = lc[bin];
            if (cum3 < k3 && cum3 + cb >= k3) { b3 = bin; r3 = k3 - cum3; break; }
            cum3 += cb;
            S3   += (double)ls[bin];
        }
        const float tval = __uint_as_float((pref << 7) | (unsigned)b3);
        const double total = st_S[row] + sS2 + S3 + (double)r3 * (double)tval;
        atomicAdd(accum, total);                 // device-scope f64 atomic
        __threadfence();
        const unsigned ticket =
            __hip_atomic_fetch_add(done, 1u, __ATOMIC_ACQ_REL, SCOPE);
        if (ticket == BN - 1) {                  // last row writes the mean
            const double a2 =
                __hip_atomic_load(accum, __ATOMIC_RELAXED, SCOPE);
            out[0] = (float)(a2 / ((double)BN * (double)topk_count(sp)));
        }
    }
}

// ======================= launch =============================================
extern "C" void kernel_launch(void* const* d_in, const int* in_sizes, int n_in,
                              void* d_out, int out_size, void* d_ws, size_t ws_size,
                              hipStream_t stream)
{
    (void)in_sizes; (void)n_in; (void)out_size; (void)ws_size;
    const float* in  = (const float*)d_in[0];
    const int*   tgt = (const int*)d_in[1];
    const int*   sp  = (const int*)d_in[2];

    char* ws = (char*)d_ws;
    float*    nll   = (float*)(ws + OFF_NLL);
    float*    cand  = (float*)(ws + OFF_CAND);
    unsigned* ghist = (unsigned*)(ws + OFF_GH);
    int*      ccnt  = (int*)(ws + OFF_CCNT);
    double*   st_S  = (double*)(ws + OFF_SS);
    double*   accum = (double*)(ws + OFF_ACC);
    unsigned* done  = (unsigned*)(ws + OFF_DONE);
    int*      st_b1 = (int*)(ws + OFF_B1);
    int*      st_r1 = (int*)(ws + OFF_R1);

    // zero: ghist + ccnt + st_S + accum + done (contiguous)
    hipMemsetAsync(ws + OFF_GH, 0, ZERO_END - OFF_GH, stream);

    k_hist1  <<<BN * BPR,   256, 0, stream>>>(in, tgt, nll, ghist);
    k_scan   <<<BN,         256, 0, stream>>>(ghist, sp, st_b1, st_r1);
    k_compact<<<BN * BPR_C, 256, 0, stream>>>(nll, st_b1, cand, ccnt, st_S);
    k_resolve<<<BN,         256, 0, stream>>>(cand, ccnt, st_b1, st_r1, st_S,
                                              sp, accum, done, (float*)d_out);
}

// Round 8
// 246.360 us; speedup vs baseline: 3.5286x; 1.0116x over previous
//
#include <hip/hip_runtime.h>

#define BN    64
#define KCLS  3
#define PPIX  147456
#define NB1   4096
#define NB3   128
#define CAP   8192

// shared streaming geometry (k_hist1 AND k_scompact):
// 64 rows x 32 chunks = 2048 blocks = 8 blocks/CU, 1152 float4/block.
// IDENTICAL grids => identical block->XCD placement => compact's nll read is
// XCD-local to k1's nll write.
#define BPR    32
#define F4PB   (PPIX / 4 / BPR)     // 1152 float4 groups per block
#define PXB    (F4PB * 4)           // 4608 pixels per block

#define SCOPE __HIP_MEMORY_SCOPE_AGENT

// ---------------- workspace layout (bytes) ----------------
static const size_t OFF_NLL  = 0;                                   // 37,748,736
static const size_t OFF_CAND = OFF_NLL + (size_t)BN * PPIX * 4;     // 2 MB
static const size_t OFF_GH   = OFF_CAND + (size_t)BN * CAP * 4;     // 1 MB (zeroed)
static const size_t OFF_CCNT = OFF_GH + (size_t)BN * NB1 * 4;       // 256 B (zeroed)
static const size_t OFF_SS   = OFF_CCNT + 256;                      // 512 B (zeroed)
static const size_t OFF_ACC  = OFF_SS + 512;                        // 8 B   (zeroed)
static const size_t OFF_DONE = OFF_ACC + 8;                         // 8 B   (zeroed)
static const size_t ZERO_END = OFF_DONE + 8;
static const size_t OFF_B1   = ZERO_END;                            // st_b1 (64 ints)
static const size_t OFF_R1   = ZERO_END + 256;                      // st_r1 (64 ints)

__device__ __forceinline__ unsigned topk_count(const int* sp_ptr) {
    double sp = (double)sp_ptr[0];
    if (sp > 1.0) sp = 1.0;
    return (unsigned)(sp * 0.15 * (double)PPIX + (1.0 - sp) * (double)PPIX);
}

__device__ __forceinline__ float sel_nll(int t, float a, float b, float c) {
    float lp = (t == 0) ? a : ((t == 1) ? b : ((t == 2) ? c : 0.0f));
    return fmaxf(-lp, 0.0f);   // nll >= 0; kill -0.0
}

// ---------------- kernel 1: NLL select + store + count histogram ------------
// (byte-identical to verified r4/r7 version, ~69us)
__global__ __launch_bounds__(256) void k_hist1(
    const float* __restrict__ in, const int* __restrict__ tgt,
    float* __restrict__ nll, unsigned* __restrict__ cnt1)
{
    __shared__ unsigned lc[NB1];   // 16 KB -> 8 blocks/CU by LDS
    const int tid = threadIdx.x;
    for (int i = tid; i < NB1; i += 256) lc[i] = 0u;
    __syncthreads();

    const int row   = blockIdx.x / BPR;
    const int chunk = blockIdx.x % BPR;
    const float4* p0 = (const float4*)(in + (size_t)row * KCLS * PPIX);
    const float4* p1 = p0 + PPIX / 4;
    const float4* p2 = p1 + PPIX / 4;
    const int4*   t4 = (const int4*)(tgt + (size_t)row * PPIX);
    float4*       n4 = (float4*)(nll + (size_t)row * PPIX);
    const int base = chunk * F4PB;
    const bool tail = (tid < (F4PB - 4 * 256));   // tid < 128 does a 5th group

    int idx_c = base + tid;
    int4   t_c = t4[idx_c];
    float4 a_c = p0[idx_c];
    float4 b_c = p1[idx_c];
    float4 c_c = p2[idx_c];

    #pragma unroll
    for (int j = 0; j < 4; ++j) {
        int idx_n = 0;
        int4 t_n; float4 a_n, b_n, c_n;
        const bool have_next = (j < 3) || tail;
        if (have_next) {
            idx_n = base + (j + 1) * 256 + tid;
            t_n = t4[idx_n];
            a_n = p0[idx_n];
            b_n = p1[idx_n];
            c_n = p2[idx_n];
        }

        float4 v;
        v.x = sel_nll(t_c.x, a_c.x, b_c.x, c_c.x);
        v.y = sel_nll(t_c.y, a_c.y, b_c.y, c_c.y);
        v.z = sel_nll(t_c.z, a_c.z, b_c.z, c_c.z);
        v.w = sel_nll(t_c.w, a_c.w, b_c.w, c_c.w);
        n4[idx_c] = v;
        atomicAdd(&lc[__float_as_uint(v.x) >> 19], 1u);
        atomicAdd(&lc[__float_as_uint(v.y) >> 19], 1u);
        atomicAdd(&lc[__float_as_uint(v.z) >> 19], 1u);
        atomicAdd(&lc[__float_as_uint(v.w) >> 19], 1u);

        idx_c = idx_n; t_c = t_n; a_c = a_n; b_c = b_n; c_c = c_n;
    }

    if (tail) {
        float4 v;
        v.x = sel_nll(t_c.x, a_c.x, b_c.x, c_c.x);
        v.y = sel_nll(t_c.y, a_c.y, b_c.y, c_c.y);
        v.z = sel_nll(t_c.z, a_c.z, b_c.z, c_c.z);
        v.w = sel_nll(t_c.w, a_c.w, b_c.w, c_c.w);
        n4[idx_c] = v;
        atomicAdd(&lc[__float_as_uint(v.x) >> 19], 1u);
        atomicAdd(&lc[__float_as_uint(v.y) >> 19], 1u);
        atomicAdd(&lc[__float_as_uint(v.z) >> 19], 1u);
        atomicAdd(&lc[__float_as_uint(v.w) >> 19], 1u);
    }
    __syncthreads();

    unsigned* gc = cnt1 + (size_t)row * NB1;
    for (int i = tid; i < NB1; i += 256) {
        const unsigned cc = lc[i];
        if (cc) atomicAdd(&gc[i], cc);
    }
}

// ---------------- kernel 2: scan (per-block, redundant) + compact -----------
// SAME grid geometry as k_hist1 (2048 blocks, 1152 f4/block) so each block
// reads back the nll chunk its k1 twin wrote (XCD-local L2/L3).
// Scan math byte-identical to verified k_scan; compact body = verified r0
// pattern (LDS stage, ONE ccnt atomic/block, plain stores). Scan scratch is
// overlaid on the stage array. f64 S_above via deterministic shuffle tree.
__global__ __launch_bounds__(256) void k_scompact(
    const float* __restrict__ nll, const unsigned* __restrict__ ghist,
    const int* __restrict__ sp, float* __restrict__ cand,
    int* __restrict__ ccnt, double* __restrict__ st_S,
    int* __restrict__ st_b, int* __restrict__ st_r)
{
    __shared__ float  stage[PXB];      // 18 KB; scan overlays first 1 KB
    __shared__ double wsum[4];         // per-wave f64 partials
    __shared__ int s_b1, s_r1, lcnt, gbase;

    const int tid   = threadIdx.x;
    const int row   = blockIdx.x / BPR;
    const int chunk = blockIdx.x % BPR;

    // ---- level-1 scan (verified k_scan logic; csum overlaid on stage) ----
    {
        unsigned* csum = (unsigned*)stage;
        const unsigned* c = ghist + (size_t)row * NB1;
        unsigned cl[16]; unsigned cacc = 0;
        const int base = tid * 16;
        #pragma unroll
        for (int i = 0; i < 16; ++i) {
            cl[i] = c[NB1 - 1 - (base + i)];
            cacc += cl[i];
        }
        csum[tid] = cacc;
        __syncthreads();
        for (int off = 1; off < 256; off <<= 1) {
            unsigned t2 = (tid >= off) ? csum[tid - off] : 0u;
            __syncthreads();
            csum[tid] += t2;
            __syncthreads();
        }
        const unsigned k = topk_count(sp);
        unsigned cum = tid ? csum[tid - 1] : 0u;
        #pragma unroll
        for (int i = 0; i < 16; ++i) {
            const unsigned cb = cl[i];
            if (cum < k && cum + cb >= k) {      // exactly one (thread,i) hits
                s_b1 = NB1 - 1 - (base + i);
                s_r1 = (int)(k - cum);
            }
            cum += cb;
        }
        if (tid == 0) lcnt = 0;
    }
    __syncthreads();
    if (chunk == 0 && tid == 0) {       // publish for k_resolve
        st_b[row] = s_b1;
        st_r[row] = s_r1;
    }

    // ---- stream this chunk: S_above (f64) + stage bin-b1 candidates ----
    const unsigned b1 = (unsigned)s_b1;
    const unsigned lo = b1 << 19;
    const unsigned hi = (b1 + 1u) << 19;   // b1==4095 -> 0x80000000 > all v>=0
    const float4* n4 = (const float4*)(nll + (size_t)row * PPIX);
    const int base = chunk * F4PB;

    double acc = 0.0;
    #pragma unroll
    for (int j = 0; j < 5; ++j) {
        if (j == 4 && tid >= (F4PB - 4 * 256)) break;   // tail: tid<128 only
        const float4 f = n4[base + j * 256 + tid];
        const float vv[4] = {f.x, f.y, f.z, f.w};
        #pragma unroll
        for (int q = 0; q < 4; ++q) {
            const unsigned u = __float_as_uint(vv[q]);
            if (u >= hi) {
                acc += (double)vv[q];
            } else if (u >= lo) {
                const int s = atomicAdd(&lcnt, 1);
                stage[s] = vv[q];                // worst case 4608 == PXB
            }
        }
    }

    // deterministic wave-shuffle f64 reduce, then 4 partials
    #pragma unroll
    for (int off = 32; off > 0; off >>= 1) acc += __shfl_down(acc, off, 64);
    if ((tid & 63) == 0) wsum[tid >> 6] = acc;
    __syncthreads();
    if (tid == 0) {
        atomicAdd(&st_S[row], (wsum[0] + wsum[1]) + (wsum[2] + wsum[3]));
        gbase = atomicAdd(&ccnt[row], lcnt);
    }
    __syncthreads();

    const int n = lcnt, gb = gbase;
    float* cr = cand + (size_t)row * CAP;
    for (int i = tid; i < n; i += 256) {
        const int pos = gb + i;
        if (pos < CAP) cr[pos] = stage[i];
    }
}

// ---------------- kernel 3: per-row resolve (levels 2+3) + fused mean -------
// (byte-identical to verified r7 k_resolve)
__global__ __launch_bounds__(256) void k_resolve(
    const float* __restrict__ cand, const int* __restrict__ ccnt,
    const int* __restrict__ st_b1, const int* __restrict__ st_r1,
    const double* __restrict__ st_S, const int* __restrict__ sp,
    double* __restrict__ accum, unsigned* __restrict__ done,
    float* __restrict__ out)
{
    __shared__ unsigned lc[NB1];
    __shared__ float    ls[NB1];
    __shared__ unsigned csum[256];
    __shared__ double   ssum[256];
    __shared__ int sb2, sr2;
    __shared__ double sS2;

    const int row = blockIdx.x, tid = threadIdx.x;
    int n = ccnt[row]; if (n > CAP) n = CAP;
    const float* cv = cand + (size_t)row * CAP;

    // ---- level 2: hist over bits[18:7] ----
    for (int i = tid; i < NB1; i += 256) { lc[i] = 0u; ls[i] = 0.0f; }
    __syncthreads();
    for (int i = tid; i < n; i += 256) {
        const float v = cv[i];
        const unsigned key = (__float_as_uint(v) >> 7) & 0xFFFu;
        atomicAdd(&lc[key], 1u);
        atomicAdd(&ls[key], v);
    }
    __syncthreads();

    unsigned cl[16]; float slv[16];
    unsigned cacc = 0; double sacc = 0.0;
    const int base = tid * 16;
    #pragma unroll
    for (int i = 0; i < 16; ++i) {
        const int bin = NB1 - 1 - (base + i);
        cl[i]  = lc[bin];
        slv[i] = ls[bin];
        cacc += cl[i];
        sacc += (double)slv[i];
    }
    csum[tid] = cacc; ssum[tid] = sacc;
    __syncthreads();
    for (int off = 1; off < 256; off <<= 1) {
        unsigned cv2 = 0; double sv = 0.0;
        if (tid >= off) { cv2 = csum[tid - off]; sv = ssum[tid - off]; }
        __syncthreads();
        csum[tid] += cv2; ssum[tid] += sv;
        __syncthreads();
    }
    const unsigned k = (unsigned)st_r1[row];
    unsigned cum = tid ? csum[tid - 1] : 0u;
    double   sS  = tid ? ssum[tid - 1] : 0.0;
    #pragma unroll
    for (int i = 0; i < 16; ++i) {
        const unsigned cb = cl[i];
        if (cum < k && cum + cb >= k) {
            sb2 = NB1 - 1 - (base + i);
            sr2 = (int)(k - cum);
            sS2 = sS;
        }
        cum += cb;
        sS  += (double)slv[i];
    }
    __syncthreads();

    // ---- level 3: 128-bin hist over bits[6:0], prefix = bits[30:7] ----
    const unsigned pref = ((unsigned)st_b1[row] << 12) | (unsigned)sb2;
    if (tid < NB3) { lc[tid] = 0u; ls[tid] = 0.0f; }
    __syncthreads();
    for (int i = tid; i < n; i += 256) {
        const float v = cv[i];
        const unsigned bits = __float_as_uint(v);
        if ((bits >> 7) == pref) {
            atomicAdd(&lc[bits & 0x7Fu], 1u);
            atomicAdd(&ls[bits & 0x7Fu], v);
        }
    }
    __syncthreads();
    if (tid == 0) {
        const unsigned k3 = (unsigned)sr2;
        unsigned cum3 = 0, r3 = 0; int b3 = 0; double S3 = 0.0;
        for (int bin = NB3 - 1; bin >= 0; --bin) {
            const unsigned cb = lc[bin];
            if (cum3 < k3 && cum3 + cb >= k3) { b3 = bin; r3 = k3 - cum3; break; }
            cum3 += cb;
            S3   += (double)ls[bin];
        }
        const float tval = __uint_as_float((pref << 7) | (unsigned)b3);
        const double total = st_S[row] + sS2 + S3 + (double)r3 * (double)tval;
        atomicAdd(accum, total);                 // device-scope f64 atomic
        __threadfence();
        const unsigned ticket =
            __hip_atomic_fetch_add(done, 1u, __ATOMIC_ACQ_REL, SCOPE);
        if (ticket == BN - 1) {                  // last row writes the mean
            const double a2 =
                __hip_atomic_load(accum, __ATOMIC_RELAXED, SCOPE);
            out[0] = (float)(a2 / ((double)BN * (double)topk_count(sp)));
        }
    }
}

// ======================= launch =============================================
extern "C" void kernel_launch(void* const* d_in, const int* in_sizes, int n_in,
                              void* d_out, int out_size, void* d_ws, size_t ws_size,
                              hipStream_t stream)
{
    (void)in_sizes; (void)n_in; (void)out_size; (void)ws_size;
    const float* in  = (const float*)d_in[0];
    const int*   tgt = (const int*)d_in[1];
    const int*   sp  = (const int*)d_in[2];

    char* ws = (char*)d_ws;
    float*    nll   = (float*)(ws + OFF_NLL);
    float*    cand  = (float*)(ws + OFF_CAND);
    unsigned* ghist = (unsigned*)(ws + OFF_GH);
    int*      ccnt  = (int*)(ws + OFF_CCNT);
    double*   st_S  = (double*)(ws + OFF_SS);
    double*   accum = (double*)(ws + OFF_ACC);
    unsigned* done  = (unsigned*)(ws + OFF_DONE);
    int*      st_b1 = (int*)(ws + OFF_B1);
    int*      st_r1 = (int*)(ws + OFF_R1);

    // zero: ghist + ccnt + st_S + accum + done (contiguous)
    hipMemsetAsync(ws + OFF_GH, 0, ZERO_END - OFF_GH, stream);

    k_hist1   <<<BN * BPR, 256, 0, stream>>>(in, tgt, nll, ghist);
    k_scompact<<<BN * BPR, 256, 0, stream>>>(nll, ghist, sp, cand, ccnt, st_S,
                                             st_b1, st_r1);
    k_resolve <<<BN,       256, 0, stream>>>(cand, ccnt, st_b1, st_r1, st_S,
                                             sp, accum, done, (float*)d_out);
}